// Round 2
// baseline (2395.324 us; speedup 1.0000x reference)
//
#include <hip/hip_runtime.h>
#include <math.h>

#define N_HYPS 65536
#define VOCAB  500
#define DIM    512
#define RB     32                 // rows (hypotheses) per block
#define NBLK   (N_HYPS / RB)      // 2048 blocks
#define KK     16                 // K-chunk staged in LDS (16 -> LDS ~97KB)
#define SAS    516                // padded stride (floats), keeps 16B alignment
#define SBS    516
#define NEGF   (-1.0e30f)

// ---------------------------------------------------------------------------
// Fused: embed -> grouped conv1d -> relu -> proj GEMM -> +enc,tanh -> joiner
// GEMM -> log_softmax -> per-block top-4 candidates.
// Block = 256 threads (4 waves), owns 32 full rows. LDS ~97KB -> 1 block/CU.
// ---------------------------------------------------------------------------
__global__ __launch_bounds__(256) void fused_main(
    const int*   __restrict__ dec_in,     // (N,2) int32
    const float* __restrict__ enc,        // (N,512)
    const float* __restrict__ hyp_lp,     // (N)
    const float* __restrict__ embed,      // (500,512)
    const float* __restrict__ conv_w,     // (512,4,2)
    const float* __restrict__ proj_w,     // (512,512)
    const float* __restrict__ proj_b,     // (512)
    const float* __restrict__ joiner_w,   // (500,512)
    const float* __restrict__ joiner_b,   // (500)
    float* __restrict__ cand_v,           // (NBLK*4)
    int*   __restrict__ cand_i)           // (NBLK*4)
{
    __shared__ float sA[RB * SAS];        // dec activations, later tanh(act)
    __shared__ float sB[KK * SBS];        // transposed weight k-panel
    __shared__ float s_wv[4];
    __shared__ int   s_wi[4];
    __shared__ float s_pv[4];
    __shared__ int   s_pi[4];

    const int tid  = threadIdx.x;
    const int row0 = blockIdx.x * RB;

    // ---- Phase 1: embedding gather + grouped conv (k=2, groups of 4) + relu
    {
        const int r    = tid >> 3;            // 0..31
        const int c0   = (tid & 7) << 6;      // 64 channels per thread
        const int grow = row0 + r;
        const int tok0 = dec_in[grow * 2 + 0];
        const int tok1 = dec_in[grow * 2 + 1];
        const float z0 = (tok0 >= 0) ? 1.f : 0.f;
        const float z1 = (tok1 >= 0) ? 1.f : 0.f;
        const float4* e0p = (const float4*)(embed + (size_t)(tok0 > 0 ? tok0 : 0) * DIM);
        const float4* e1p = (const float4*)(embed + (size_t)(tok1 > 0 ? tok1 : 0) * DIM);
        #pragma unroll
        for (int g = 0; g < 16; ++g) {
            const int c = c0 + g * 4;         // group-aligned (c % 4 == 0)
            float4 e0 = e0p[c >> 2];
            float4 e1 = e1p[c >> 2];
            e0.x *= z0; e0.y *= z0; e0.z *= z0; e0.w *= z0;
            e1.x *= z1; e1.y *= z1; e1.z *= z1; e1.w *= z1;
            #pragma unroll
            for (int j = 0; j < 4; ++j) {
                const int cc = c + j;
                // conv_w[cc][ic][t]: 8 floats = {i0t0,i0t1,i1t0,i1t1, i2t0,i2t1,i3t0,i3t1}
                const float4 wa = *(const float4*)(conv_w + cc * 8);
                const float4 wb = *(const float4*)(conv_w + cc * 8 + 4);
                const float v = e0.x*wa.x + e1.x*wa.y + e0.y*wa.z + e1.y*wa.w
                              + e0.z*wb.x + e1.z*wb.y + e0.w*wb.z + e1.w*wb.w;
                sA[r * SAS + cc] = fmaxf(v, 0.f);
            }
        }
    }
    __syncthreads();

    const int tr = tid >> 5;   // 0..7 -> rows tr*4..tr*4+3
    const int tc = tid & 31;   // cols tc*4 + 128*j + ii

    float acc[4][16];

    // ================= GEMM1: C = dec @ proj_w^T =================
    #pragma unroll
    for (int i = 0; i < 4; ++i)
        #pragma unroll
        for (int j = 0; j < 16; ++j) acc[i][j] = 0.f;

    for (int k0 = 0; k0 < DIM; k0 += KK) {
        __syncthreads();
        // stage sB[kk][o] = proj_w[o][k0+kk]   (KK*512 = 8192 floats)
        #pragma unroll
        for (int j = 0; j < 8; ++j) {
            const int gid = tid + j * 256;        // 0..2047
            const int o   = gid >> 2;             // 0..511
            const int k4  = (gid & 3) << 2;       // 0,4,8,12
            const float4 v = *(const float4*)(proj_w + o * DIM + k0 + k4);
            sB[(k4 + 0) * SBS + o] = v.x;
            sB[(k4 + 1) * SBS + o] = v.y;
            sB[(k4 + 2) * SBS + o] = v.z;
            sB[(k4 + 3) * SBS + o] = v.w;
        }
        __syncthreads();
        #pragma unroll
        for (int kk = 0; kk < KK; kk += 4) {
            float4 a4[4];
            #pragma unroll
            for (int i = 0; i < 4; ++i)
                a4[i] = *(const float4*)(&sA[(tr * 4 + i) * SAS + k0 + kk]);
            #pragma unroll
            for (int dk = 0; dk < 4; ++dk) {
                float4 b4[4];
                #pragma unroll
                for (int j = 0; j < 4; ++j)
                    b4[j] = *(const float4*)(&sB[(kk + dk) * SBS + tc * 4 + 128 * j]);
                #pragma unroll
                for (int i = 0; i < 4; ++i) {
                    const float av = ((const float*)&a4[i])[dk];
                    #pragma unroll
                    for (int j = 0; j < 4; ++j) {
                        acc[i][j*4+0] = fmaf(av, b4[j].x, acc[i][j*4+0]);
                        acc[i][j*4+1] = fmaf(av, b4[j].y, acc[i][j*4+1]);
                        acc[i][j*4+2] = fmaf(av, b4[j].z, acc[i][j*4+2]);
                        acc[i][j*4+3] = fmaf(av, b4[j].w, acc[i][j*4+3]);
                    }
                }
            }
        }
    }
    __syncthreads();   // all sA reads done before overwrite

    // epilogue 1: act = tanh(C + proj_b + enc) -> back to sA
    #pragma unroll
    for (int i = 0; i < 4; ++i) {
        const int rr = tr * 4 + i;
        const size_t erow = (size_t)(row0 + rr) * DIM;
        #pragma unroll
        for (int j = 0; j < 4; ++j) {
            const int o = tc * 4 + 128 * j;
            const float4 e  = *(const float4*)(enc + erow + o);
            const float4 pb = *(const float4*)(proj_b + o);
            sA[rr * SAS + o + 0] = tanhf(acc[i][j*4+0] + pb.x + e.x);
            sA[rr * SAS + o + 1] = tanhf(acc[i][j*4+1] + pb.y + e.y);
            sA[rr * SAS + o + 2] = tanhf(acc[i][j*4+2] + pb.z + e.z);
            sA[rr * SAS + o + 3] = tanhf(acc[i][j*4+3] + pb.w + e.w);
        }
    }

    // ================= GEMM2: logits = act @ joiner_w^T (cols padded to 512)
    #pragma unroll
    for (int i = 0; i < 4; ++i)
        #pragma unroll
        for (int j = 0; j < 16; ++j) acc[i][j] = 0.f;

    for (int k0 = 0; k0 < DIM; k0 += KK) {
        __syncthreads();
        #pragma unroll
        for (int j = 0; j < 8; ++j) {
            const int gid = tid + j * 256;
            const int o   = gid >> 2;
            const int k4  = (gid & 3) << 2;
            float4 v = make_float4(0.f, 0.f, 0.f, 0.f);
            if (o < VOCAB) v = *(const float4*)(joiner_w + o * DIM + k0 + k4);
            sB[(k4 + 0) * SBS + o] = v.x;
            sB[(k4 + 1) * SBS + o] = v.y;
            sB[(k4 + 2) * SBS + o] = v.z;
            sB[(k4 + 3) * SBS + o] = v.w;
        }
        __syncthreads();
        #pragma unroll
        for (int kk = 0; kk < KK; kk += 4) {
            float4 a4[4];
            #pragma unroll
            for (int i = 0; i < 4; ++i)
                a4[i] = *(const float4*)(&sA[(tr * 4 + i) * SAS + k0 + kk]);
            #pragma unroll
            for (int dk = 0; dk < 4; ++dk) {
                float4 b4[4];
                #pragma unroll
                for (int j = 0; j < 4; ++j)
                    b4[j] = *(const float4*)(&sB[(kk + dk) * SBS + tc * 4 + 128 * j]);
                #pragma unroll
                for (int i = 0; i < 4; ++i) {
                    const float av = ((const float*)&a4[i])[dk];
                    #pragma unroll
                    for (int j = 0; j < 4; ++j) {
                        acc[i][j*4+0] = fmaf(av, b4[j].x, acc[i][j*4+0]);
                        acc[i][j*4+1] = fmaf(av, b4[j].y, acc[i][j*4+1]);
                        acc[i][j*4+2] = fmaf(av, b4[j].z, acc[i][j*4+2]);
                        acc[i][j*4+3] = fmaf(av, b4[j].w, acc[i][j*4+3]);
                    }
                }
            }
        }
    }

    // ---- Phase 4: +joiner_b, row logsumexp (32-lane half reduce), log-probs
    #pragma unroll
    for (int i = 0; i < 4; ++i) {
        #pragma unroll
        for (int x = 0; x < 16; ++x) {
            const int o = tc * 4 + 128 * (x >> 2) + (x & 3);
            if (o < VOCAB) acc[i][x] += joiner_b[o];
            else           acc[i][x]  = NEGF;
        }
        float mm = NEGF;
        #pragma unroll
        for (int x = 0; x < 16; ++x) mm = fmaxf(mm, acc[i][x]);
        #pragma unroll
        for (int s = 16; s >= 1; s >>= 1) mm = fmaxf(mm, __shfl_xor(mm, s, 64));
        float ss = 0.f;
        #pragma unroll
        for (int x = 0; x < 16; ++x) ss += expf(acc[i][x] - mm);
        #pragma unroll
        for (int s = 16; s >= 1; s >>= 1) ss += __shfl_xor(ss, s, 64);
        const float lse = mm + logf(ss);
        const float h   = hyp_lp[row0 + tr * 4 + i];
        #pragma unroll
        for (int x = 0; x < 16; ++x) acc[i][x] = acc[i][x] - lse + h;
    }

    // ---- block top-4 by iterated argmax (tie-break: lower flat index)
    int pick0 = -1, pick1 = -1, pick2 = -1;
    #pragma unroll
    for (int it = 0; it < 4; ++it) {
        float bv = -INFINITY; int bi = 0x7fffffff;
        #pragma unroll
        for (int i = 0; i < 4; ++i) {
            const int rowbase = (row0 + tr * 4 + i) * VOCAB;
            #pragma unroll
            for (int x = 0; x < 16; ++x) {
                const int o = tc * 4 + 128 * (x >> 2) + (x & 3);
                if (o < VOCAB) {
                    const int idx = rowbase + o;
                    bool excl = false;
                    if (it > 0) excl = excl || (idx == pick0);
                    if (it > 1) excl = excl || (idx == pick1);
                    if (it > 2) excl = excl || (idx == pick2);
                    const float v = acc[i][x];
                    if (!excl && (v > bv || (v == bv && idx < bi))) { bv = v; bi = idx; }
                }
            }
        }
        #pragma unroll
        for (int s = 32; s >= 1; s >>= 1) {
            const float ov = __shfl_xor(bv, s, 64);
            const int   oi = __shfl_xor(bi, s, 64);
            if (ov > bv || (ov == bv && oi < bi)) { bv = ov; bi = oi; }
        }
        if ((tid & 63) == 0) { s_wv[tid >> 6] = bv; s_wi[tid >> 6] = bi; }
        __syncthreads();
        if (tid == 0) {
            float pv = s_wv[0]; int pi = s_wi[0];
            for (int w = 1; w < 4; ++w)
                if (s_wv[w] > pv || (s_wv[w] == pv && s_wi[w] < pi)) { pv = s_wv[w]; pi = s_wi[w]; }
            s_pv[it] = pv; s_pi[it] = pi;
        }
        __syncthreads();
        if (it == 0) pick0 = s_pi[0];
        if (it == 1) pick1 = s_pi[1];
        if (it == 2) pick2 = s_pi[2];
    }
    if (tid < 4) {
        cand_v[blockIdx.x * 4 + tid] = s_pv[tid];
        cand_i[blockIdx.x * 4 + tid] = s_pi[tid];
    }
}

// ---------------------------------------------------------------------------
// Final: reduce NBLK*4 = 8192 candidates to global top-4, write 16 outputs.
// ---------------------------------------------------------------------------
__global__ __launch_bounds__(256) void final_topk(
    const float* __restrict__ cand_v,
    const int*   __restrict__ cand_i,
    const float* __restrict__ hyp_lp,
    float* __restrict__ out)
{
    __shared__ float s_wv[4];
    __shared__ int   s_wi[4];
    __shared__ float s_pv[4];
    __shared__ int   s_pi[4];
    const int tid = threadIdx.x;

    float v[32]; int ix[32];
    #pragma unroll
    for (int j = 0; j < 32; ++j) {
        const int e = tid + j * 256;
        v[j]  = cand_v[e];
        ix[j] = cand_i[e];
    }
    int pick0 = -1, pick1 = -1, pick2 = -1;
    #pragma unroll
    for (int it = 0; it < 4; ++it) {
        float bv = -INFINITY; int bi = 0x7fffffff;
        #pragma unroll
        for (int j = 0; j < 32; ++j) {
            bool excl = false;
            if (it > 0) excl = excl || (ix[j] == pick0);
            if (it > 1) excl = excl || (ix[j] == pick1);
            if (it > 2) excl = excl || (ix[j] == pick2);
            if (!excl && (v[j] > bv || (v[j] == bv && ix[j] < bi))) { bv = v[j]; bi = ix[j]; }
        }
        #pragma unroll
        for (int s = 32; s >= 1; s >>= 1) {
            const float ov = __shfl_xor(bv, s, 64);
            const int   oi = __shfl_xor(bi, s, 64);
            if (ov > bv || (ov == bv && oi < bi)) { bv = ov; bi = oi; }
        }
        if ((tid & 63) == 0) { s_wv[tid >> 6] = bv; s_wi[tid >> 6] = bi; }
        __syncthreads();
        if (tid == 0) {
            float pv = s_wv[0]; int pi = s_wi[0];
            for (int w = 1; w < 4; ++w)
                if (s_wv[w] > pv || (s_wv[w] == pv && s_wi[w] < pi)) { pv = s_wv[w]; pi = s_wi[w]; }
            s_pv[it] = pv; s_pi[it] = pi;
        }
        __syncthreads();
        if (it == 0) pick0 = s_pi[0];
        if (it == 1) pick1 = s_pi[1];
        if (it == 2) pick2 = s_pi[2];
    }
    if (tid == 0) {
        #pragma unroll
        for (int it = 0; it < 4; ++it) {
            const float val = s_pv[it];
            const int   idx = s_pi[it];
            const int   hyp = idx / VOCAB;
            const int   tok = idx - hyp * VOCAB;
            out[it]      = val;                           // hyps_topk_log_prob
            out[4 + it]  = expf(val - hyp_lp[hyp]);       // tokens_topk_prob
            out[8 + it]  = (float)hyp;                    // topk_hyp_indexes
            out[12 + it] = (float)tok;                    // topk_token_indexes
        }
    }
}

extern "C" void kernel_launch(void* const* d_in, const int* in_sizes, int n_in,
                              void* d_out, int out_size, void* d_ws, size_t ws_size,
                              hipStream_t stream)
{
    const int*   dec_in   = (const int*)d_in[0];
    const float* enc      = (const float*)d_in[1];
    const float* hyp_lp   = (const float*)d_in[2];
    const float* embed    = (const float*)d_in[3];
    const float* conv_w   = (const float*)d_in[4];
    const float* proj_w   = (const float*)d_in[5];
    const float* proj_b   = (const float*)d_in[6];
    const float* joiner_w = (const float*)d_in[7];
    const float* joiner_b = (const float*)d_in[8];
    // beam (d_in[9]) is the compile-time constant 4.

    float* cand_v = (float*)d_ws;
    int*   cand_i = (int*)((char*)d_ws + (size_t)NBLK * 4 * sizeof(float));
    float* out    = (float*)d_out;

    fused_main<<<NBLK, 256, 0, stream>>>(dec_in, enc, hyp_lp, embed, conv_w,
                                         proj_w, proj_b, joiner_w, joiner_b,
                                         cand_v, cand_i);
    final_topk<<<1, 256, 0, stream>>>(cand_v, cand_i, hyp_lp, out);
}

// Round 3
// 723.374 us; speedup vs baseline: 3.3113x; 3.3113x over previous
//
#include <hip/hip_runtime.h>
#include <math.h>

#define N_HYPS 65536
#define VOCAB  500
#define DIM    512
#define RB     64
#define NBLK   (N_HYPS / RB)      // 1024 blocks
#define NEGF   (-1.0e30f)
#define SAS    520                // sA row stride (shorts): 1040B, 16B-aligned
#define SBS    40                 // sB row stride (shorts): 80B, 16B-aligned

typedef short bf16x8 __attribute__((ext_vector_type(8)));   // 4 VGPR MFMA A/B frag
typedef short bf16x4 __attribute__((ext_vector_type(4)));
typedef float f32x4  __attribute__((ext_vector_type(4)));   // MFMA C/D frag

__device__ __forceinline__ short f2bf(float f) {
    union { float f; unsigned u; } x; x.f = f;
    unsigned r = x.u + 0x7fffu + ((x.u >> 16) & 1u);        // RNE
    return (short)(r >> 16);
}
__device__ __forceinline__ float bf2f(short s) {
    union { unsigned u; float f; } x;
    x.u = ((unsigned)(unsigned short)s) << 16;
    return x.f;
}

// ---------------------------------------------------------------------------
// Pre-pass: fp32 weights -> bf16 in workspace. joiner_w zero-padded to 512 rows.
// ---------------------------------------------------------------------------
__global__ __launch_bounds__(256) void convert_weights(
    const float* __restrict__ proj_w, const float* __restrict__ joiner_w,
    short* __restrict__ Wp, short* __restrict__ Wj)
{
    const int i = blockIdx.x * 256 + threadIdx.x;           // 0..262143
    Wp[i] = f2bf(proj_w[i]);
    Wj[i] = (i < VOCAB * DIM) ? f2bf(joiner_w[i]) : (short)0;
}

// ---------------------------------------------------------------------------
// One GEMM pass: acc[rt][ct] += sA(64xK) @ W^T, K=512, 16 K-steps of 32.
// Wave w owns cols w*128..+128 (8 col-frags); rows: all 4 row-frags (64 rows).
// ---------------------------------------------------------------------------
__device__ __forceinline__ void gemm_pass(
    const short* __restrict__ Wb,   // (512,512) bf16 row-major (B^T layout)
    const short* sA, short* sB,
    f32x4 (&acc)[4][8], int tid)
{
    const int lm  = tid & 15;
    const int lj  = (tid >> 4) & 3;
    const int c0w = (tid >> 6) * 128;
    for (int ks = 0; ks < 16; ++ks) {
        __syncthreads();                     // prev compute done: sB reusable
        #pragma unroll
        for (int j = 0; j < 8; ++j) {        // stage 512x32 bf16 slice (32KB)
            const int chunk = tid + j * 256; // 0..2047
            const int c     = chunk >> 2;    // W row (= output col) 0..511
            const int part  = chunk & 3;     // k sub-offset *8
            const float4 v  = *(const float4*)(const void*)(Wb + c * DIM + ks * 32 + part * 8);
            *(float4*)(void*)(&sB[c * SBS + part * 8]) = v;
        }
        __syncthreads();
        bf16x8 a[4];
        #pragma unroll
        for (int rt = 0; rt < 4; ++rt)
            a[rt] = *(const bf16x8*)(const void*)(&sA[(rt * 16 + lm) * SAS + ks * 32 + 8 * lj]);
        #pragma unroll
        for (int ct = 0; ct < 8; ++ct) {
            const bf16x8 b = *(const bf16x8*)(const void*)(&sB[(c0w + ct * 16 + lm) * SBS + 8 * lj]);
            #pragma unroll
            for (int rt = 0; rt < 4; ++rt)
                acc[rt][ct] = __builtin_amdgcn_mfma_f32_16x16x32_bf16(a[rt], b, acc[rt][ct], 0, 0, 0);
        }
    }
}

// ---------------------------------------------------------------------------
// Fused main: embed+conv+relu -> MFMA GEMM1 -> +b,+enc,tanh -> MFMA GEMM2
// -> +b, log_softmax -> per-block top-4.
// ---------------------------------------------------------------------------
__global__ __launch_bounds__(256) void fused_main(
    const int*   __restrict__ dec_in,
    const float* __restrict__ enc,
    const float* __restrict__ hyp_lp,
    const float* __restrict__ embed,
    const float* __restrict__ conv_w,
    const float* __restrict__ proj_b,
    const float* __restrict__ joiner_b,
    const short* __restrict__ Wp,
    const short* __restrict__ Wj,
    float* __restrict__ cand_v,
    int*   __restrict__ cand_i)
{
    __shared__ short sA[RB * SAS];          // 66.5 KB: A (bf16), later tanh acts
    __shared__ short sB[DIM * SBS];         // 41 KB: weight K-slice
    __shared__ float sJb[DIM];
    __shared__ float sHyp[RB];
    __shared__ float sRed[4 * RB];
    __shared__ float s_wv[4]; __shared__ int s_wi[4];
    __shared__ float s_pv[4]; __shared__ int s_pi[4];

    const int tid  = threadIdx.x;
    const int row0 = blockIdx.x * RB;

    for (int j = tid; j < DIM; j += 256) sJb[j] = (j < VOCAB) ? joiner_b[j] : 0.f;
    if (tid < RB) sHyp[tid] = hyp_lp[row0 + tid];

    // ---- Phase 1: embed gather + grouped conv (k=2, in/out groups of 4) + relu
    {
        const int r    = tid >> 2;            // 0..63
        const int c0   = (tid & 3) * 128;     // 128 channels/thread
        const int grow = row0 + r;
        const int tok0 = dec_in[grow * 2 + 0];
        const int tok1 = dec_in[grow * 2 + 1];
        const float z0 = (tok0 >= 0) ? 1.f : 0.f;
        const float z1 = (tok1 >= 0) ? 1.f : 0.f;
        const float4* e0p = (const float4*)(embed + (size_t)(tok0 > 0 ? tok0 : 0) * DIM);
        const float4* e1p = (const float4*)(embed + (size_t)(tok1 > 0 ? tok1 : 0) * DIM);
        #pragma unroll 4
        for (int g = 0; g < 32; ++g) {
            const int c = c0 + g * 4;
            float4 e0 = e0p[c >> 2];
            float4 e1 = e1p[c >> 2];
            e0.x *= z0; e0.y *= z0; e0.z *= z0; e0.w *= z0;
            e1.x *= z1; e1.y *= z1; e1.z *= z1; e1.w *= z1;
            bf16x4 pk;
            #pragma unroll
            for (int j = 0; j < 4; ++j) {
                const int cc = c + j;
                const float4 wa = *(const float4*)(conv_w + cc * 8);
                const float4 wb = *(const float4*)(conv_w + cc * 8 + 4);
                const float v = e0.x*wa.x + e1.x*wa.y + e0.y*wa.z + e1.y*wa.w
                              + e0.z*wb.x + e1.z*wb.y + e0.w*wb.z + e1.w*wb.w;
                pk[j] = f2bf(fmaxf(v, 0.f));
            }
            *(bf16x4*)(void*)(&sA[r * SAS + c]) = pk;
        }
    }
    __syncthreads();

    const int lm  = tid & 15;
    const int lj  = (tid >> 4) & 3;
    const int w   = tid >> 6;
    const int c0w = w * 128;

    f32x4 acc[4][8];
    #pragma unroll
    for (int rt = 0; rt < 4; ++rt)
        #pragma unroll
        for (int ct = 0; ct < 8; ++ct) { acc[rt][ct][0]=0.f; acc[rt][ct][1]=0.f; acc[rt][ct][2]=0.f; acc[rt][ct][3]=0.f; }

    // ================= GEMM1 =================
    gemm_pass(Wp, sA, sB, acc, tid);
    __syncthreads();                          // all sA frag reads complete

    // epilogue 1a: raw acc -> sA (bf16, scattered)
    #pragma unroll
    for (int rt = 0; rt < 4; ++rt)
        #pragma unroll
        for (int ct = 0; ct < 8; ++ct)
            #pragma unroll
            for (int rg = 0; rg < 4; ++rg) {
                const int m = rt * 16 + 4 * lj + rg;
                const int n = c0w + ct * 16 + lm;
                sA[m * SAS + n] = f2bf(acc[rt][ct][rg]);
            }
    __syncthreads();

    // epilogue 1b: vectorized act = tanh(C + proj_b + enc), coalesced enc reads
    {
        const int r  = tid >> 2;
        const int cb = (tid & 3) * 128;
        const size_t erow = (size_t)(row0 + r) * DIM;
        #pragma unroll
        for (int ch = 0; ch < 16; ++ch) {
            const int c = cb + ch * 8;
            bf16x8 raw = *(bf16x8*)(void*)(&sA[r * SAS + c]);
            const float4 e0 = *(const float4*)(enc + erow + c);
            const float4 e1 = *(const float4*)(enc + erow + c + 4);
            const float4 b0 = *(const float4*)(proj_b + c);
            const float4 b1 = *(const float4*)(proj_b + c + 4);
            bf16x8 o;
            o[0] = f2bf(tanhf(bf2f(raw[0]) + b0.x + e0.x));
            o[1] = f2bf(tanhf(bf2f(raw[1]) + b0.y + e0.y));
            o[2] = f2bf(tanhf(bf2f(raw[2]) + b0.z + e0.z));
            o[3] = f2bf(tanhf(bf2f(raw[3]) + b0.w + e0.w));
            o[4] = f2bf(tanhf(bf2f(raw[4]) + b1.x + e1.x));
            o[5] = f2bf(tanhf(bf2f(raw[5]) + b1.y + e1.y));
            o[6] = f2bf(tanhf(bf2f(raw[6]) + b1.z + e1.z));
            o[7] = f2bf(tanhf(bf2f(raw[7]) + b1.w + e1.w));
            *(bf16x8*)(void*)(&sA[r * SAS + c]) = o;
        }
    }
    __syncthreads();

    // ================= GEMM2 =================
    #pragma unroll
    for (int rt = 0; rt < 4; ++rt)
        #pragma unroll
        for (int ct = 0; ct < 8; ++ct) { acc[rt][ct][0]=0.f; acc[rt][ct][1]=0.f; acc[rt][ct][2]=0.f; acc[rt][ct][3]=0.f; }
    gemm_pass(Wj, sA, sB, acc, tid);

    // ---- Phase 4: +joiner_b, mask pad cols, row log-softmax, + hyp_lp
    float rmx[4][4];
    #pragma unroll
    for (int rt = 0; rt < 4; ++rt)
        #pragma unroll
        for (int rg = 0; rg < 4; ++rg) rmx[rt][rg] = NEGF;
    #pragma unroll
    for (int ct = 0; ct < 8; ++ct) {
        const int n = c0w + ct * 16 + lm;
        const float jb = sJb[n];
        const bool valid = (n < VOCAB);
        #pragma unroll
        for (int rt = 0; rt < 4; ++rt)
            #pragma unroll
            for (int rg = 0; rg < 4; ++rg) {
                const float v = valid ? (acc[rt][ct][rg] + jb) : NEGF;
                acc[rt][ct][rg] = v;
                rmx[rt][rg] = fmaxf(rmx[rt][rg], v);
            }
    }
    #pragma unroll
    for (int s = 1; s <= 8; s <<= 1)
        #pragma unroll
        for (int rt = 0; rt < 4; ++rt)
            #pragma unroll
            for (int rg = 0; rg < 4; ++rg)
                rmx[rt][rg] = fmaxf(rmx[rt][rg], __shfl_xor(rmx[rt][rg], s, 64));
    if (lm == 0)
        #pragma unroll
        for (int rt = 0; rt < 4; ++rt)
            #pragma unroll
            for (int rg = 0; rg < 4; ++rg)
                sRed[w * RB + rt * 16 + 4 * lj + rg] = rmx[rt][rg];
    __syncthreads();
    float lmx[4][4];
    #pragma unroll
    for (int rt = 0; rt < 4; ++rt)
        #pragma unroll
        for (int rg = 0; rg < 4; ++rg) {
            const int m = rt * 16 + 4 * lj + rg;
            lmx[rt][rg] = fmaxf(fmaxf(sRed[m], sRed[RB + m]), fmaxf(sRed[2*RB + m], sRed[3*RB + m]));
        }
    __syncthreads();
    float rsm[4][4];
    #pragma unroll
    for (int rt = 0; rt < 4; ++rt)
        #pragma unroll
        for (int rg = 0; rg < 4; ++rg) rsm[rt][rg] = 0.f;
    #pragma unroll
    for (int ct = 0; ct < 8; ++ct)
        #pragma unroll
        for (int rt = 0; rt < 4; ++rt)
            #pragma unroll
            for (int rg = 0; rg < 4; ++rg)
                rsm[rt][rg] += __expf(acc[rt][ct][rg] - lmx[rt][rg]);
    #pragma unroll
    for (int s = 1; s <= 8; s <<= 1)
        #pragma unroll
        for (int rt = 0; rt < 4; ++rt)
            #pragma unroll
            for (int rg = 0; rg < 4; ++rg)
                rsm[rt][rg] += __shfl_xor(rsm[rt][rg], s, 64);
    if (lm == 0)
        #pragma unroll
        for (int rt = 0; rt < 4; ++rt)
            #pragma unroll
            for (int rg = 0; rg < 4; ++rg)
                sRed[w * RB + rt * 16 + 4 * lj + rg] = rsm[rt][rg];
    __syncthreads();
    float adj[4][4];
    #pragma unroll
    for (int rt = 0; rt < 4; ++rt)
        #pragma unroll
        for (int rg = 0; rg < 4; ++rg) {
            const int m = rt * 16 + 4 * lj + rg;
            const float den = sRed[m] + sRed[RB + m] + sRed[2*RB + m] + sRed[3*RB + m];
            adj[rt][rg] = sHyp[m] - (lmx[rt][rg] + __logf(den));
        }
    #pragma unroll
    for (int ct = 0; ct < 8; ++ct)
        #pragma unroll
        for (int rt = 0; rt < 4; ++rt)
            #pragma unroll
            for (int rg = 0; rg < 4; ++rg)
                acc[rt][ct][rg] += adj[rt][rg];

    // ---- block top-4 by iterated argmax (tie-break: lower flat index)
    int pick0 = -1, pick1 = -1, pick2 = -1;
    #pragma unroll
    for (int it = 0; it < 4; ++it) {
        float bv = -INFINITY; int bi = 0x7fffffff;
        #pragma unroll
        for (int ct = 0; ct < 8; ++ct) {
            const int n = c0w + ct * 16 + lm;
            if (n < VOCAB) {
                #pragma unroll
                for (int rt = 0; rt < 4; ++rt)
                    #pragma unroll
                    for (int rg = 0; rg < 4; ++rg) {
                        const int m = rt * 16 + 4 * lj + rg;
                        const int idx = (row0 + m) * VOCAB + n;
                        bool excl = false;
                        if (it > 0) excl = excl || (idx == pick0);
                        if (it > 1) excl = excl || (idx == pick1);
                        if (it > 2) excl = excl || (idx == pick2);
                        const float v = acc[rt][ct][rg];
                        if (!excl && (v > bv || (v == bv && idx < bi))) { bv = v; bi = idx; }
                    }
            }
        }
        #pragma unroll
        for (int s = 32; s >= 1; s >>= 1) {
            const float ov = __shfl_xor(bv, s, 64);
            const int   oi = __shfl_xor(bi, s, 64);
            if (ov > bv || (ov == bv && oi < bi)) { bv = ov; bi = oi; }
        }
        if ((tid & 63) == 0) { s_wv[tid >> 6] = bv; s_wi[tid >> 6] = bi; }
        __syncthreads();
        if (tid == 0) {
            float pv = s_wv[0]; int pi = s_wi[0];
            for (int ww = 1; ww < 4; ++ww)
                if (s_wv[ww] > pv || (s_wv[ww] == pv && s_wi[ww] < pi)) { pv = s_wv[ww]; pi = s_wi[ww]; }
            s_pv[it] = pv; s_pi[it] = pi;
        }
        __syncthreads();
        if (it == 0) pick0 = s_pi[0];
        if (it == 1) pick1 = s_pi[1];
        if (it == 2) pick2 = s_pi[2];
    }
    if (tid < 4) {
        cand_v[blockIdx.x * 4 + tid] = s_pv[tid];
        cand_i[blockIdx.x * 4 + tid] = s_pi[tid];
    }
}

// ---------------------------------------------------------------------------
// Final: reduce NBLK*4 = 4096 candidates to global top-4, write 16 outputs.
// ---------------------------------------------------------------------------
__global__ __launch_bounds__(256) void final_topk(
    const float* __restrict__ cand_v,
    const int*   __restrict__ cand_i,
    const float* __restrict__ hyp_lp,
    float* __restrict__ out)
{
    __shared__ float s_wv[4];
    __shared__ int   s_wi[4];
    __shared__ float s_pv[4];
    __shared__ int   s_pi[4];
    const int tid = threadIdx.x;

    float v[16]; int ix[16];
    #pragma unroll
    for (int j = 0; j < 16; ++j) {
        const int e = tid + j * 256;
        v[j]  = cand_v[e];
        ix[j] = cand_i[e];
    }
    int pick0 = -1, pick1 = -1, pick2 = -1;
    #pragma unroll
    for (int it = 0; it < 4; ++it) {
        float bv = -INFINITY; int bi = 0x7fffffff;
        #pragma unroll
        for (int j = 0; j < 16; ++j) {
            bool excl = false;
            if (it > 0) excl = excl || (ix[j] == pick0);
            if (it > 1) excl = excl || (ix[j] == pick1);
            if (it > 2) excl = excl || (ix[j] == pick2);
            if (!excl && (v[j] > bv || (v[j] == bv && ix[j] < bi))) { bv = v[j]; bi = ix[j]; }
        }
        #pragma unroll
        for (int s = 32; s >= 1; s >>= 1) {
            const float ov = __shfl_xor(bv, s, 64);
            const int   oi = __shfl_xor(bi, s, 64);
            if (ov > bv || (ov == bv && oi < bi)) { bv = ov; bi = oi; }
        }
        if ((tid & 63) == 0) { s_wv[tid >> 6] = bv; s_wi[tid >> 6] = bi; }
        __syncthreads();
        if (tid == 0) {
            float pv = s_wv[0]; int pi = s_wi[0];
            for (int ww = 1; ww < 4; ++ww)
                if (s_wv[ww] > pv || (s_wv[ww] == pv && s_wi[ww] < pi)) { pv = s_wv[ww]; pi = s_wi[ww]; }
            s_pv[it] = pv; s_pi[it] = pi;
        }
        __syncthreads();
        if (it == 0) pick0 = s_pi[0];
        if (it == 1) pick1 = s_pi[1];
        if (it == 2) pick2 = s_pi[2];
    }
    if (tid == 0) {
        #pragma unroll
        for (int it = 0; it < 4; ++it) {
            const float val = s_pv[it];
            const int   idx = s_pi[it];
            const int   hyp = idx / VOCAB;
            const int   tok = idx - hyp * VOCAB;
            out[it]      = val;                           // hyps_topk_log_prob
            out[4 + it]  = expf(val - hyp_lp[hyp]);       // tokens_topk_prob
            out[8 + it]  = (float)hyp;                    // topk_hyp_indexes
            out[12 + it] = (float)tok;                    // topk_token_indexes
        }
    }
}

extern "C" void kernel_launch(void* const* d_in, const int* in_sizes, int n_in,
                              void* d_out, int out_size, void* d_ws, size_t ws_size,
                              hipStream_t stream)
{
    const int*   dec_in   = (const int*)d_in[0];
    const float* enc      = (const float*)d_in[1];
    const float* hyp_lp   = (const float*)d_in[2];
    const float* embed    = (const float*)d_in[3];
    const float* conv_w   = (const float*)d_in[4];
    const float* proj_w   = (const float*)d_in[5];
    const float* proj_b   = (const float*)d_in[6];
    const float* joiner_w = (const float*)d_in[7];
    const float* joiner_b = (const float*)d_in[8];

    // workspace layout: Wp_bf16 (512KB) | Wj_bf16 padded (512KB) | cand_v | cand_i
    short* Wp     = (short*)d_ws;
    short* Wj     = (short*)((char*)d_ws + 524288);
    float* cand_v = (float*)((char*)d_ws + 1048576);
    int*   cand_i = (int*)  ((char*)d_ws + 1048576 + 16384);
    float* out    = (float*)d_out;

    convert_weights<<<DIM * DIM / 256, 256, 0, stream>>>(proj_w, joiner_w, Wp, Wj);
    fused_main<<<NBLK, 256, 0, stream>>>(dec_in, enc, hyp_lp, embed, conv_w,
                                         proj_b, joiner_b, Wp, Wj, cand_v, cand_i);
    final_topk<<<1, 256, 0, stream>>>(cand_v, cand_i, hyp_lp, out);
}

// Round 8
// 504.052 us; speedup vs baseline: 4.7521x; 1.4351x over previous
//
#include <hip/hip_runtime.h>
#include <math.h>

#define N_HYPS 65536
#define VOCAB  500
#define DIM    512
#define RB     64
#define NBLK   (N_HYPS / RB)      // 1024 blocks
#define NEGF   (-1.0e30f)
#define SAS    520                // sA row stride (shorts): 1040B, 16B-aligned

typedef short bf16x8 __attribute__((ext_vector_type(8)));   // 4 VGPR MFMA A/B frag
typedef short bf16x4 __attribute__((ext_vector_type(4)));
typedef float f32x4  __attribute__((ext_vector_type(4)));   // MFMA C/D frag

__device__ __forceinline__ short f2bf(float f) {
    union { float f; unsigned u; } x; x.f = f;
    unsigned r = x.u + 0x7fffu + ((x.u >> 16) & 1u);        // RNE
    return (short)(r >> 16);
}
__device__ __forceinline__ float bf2f(short s) {
    union { unsigned u; float f; } x;
    x.u = ((unsigned)(unsigned short)s) << 16;
    return x.f;
}

// ---------------------------------------------------------------------------
// Pre-pass: fp32 weights -> bf16 FRAGMENT-MAJOR workspace.
// Wf short-index ((nt*16+ks)*64 + lane)*8 + e  =  W[nt*16+(lane&15)][ks*32+8*(lane>>4)+e]
// so a wave's B-frag load for (col-tile nt, k-step ks) is one coalesced 1KB dwordx4.
// joiner rows >= 500 are zero-padded.
// ---------------------------------------------------------------------------
__global__ __launch_bounds__(256) void convert_weights(
    const float* __restrict__ proj_w, const float* __restrict__ joiner_w,
    short* __restrict__ Wfp, short* __restrict__ Wfj)
{
    const int g    = blockIdx.x * 256 + threadIdx.x;   // 0..65535
    const int m    = g >> 15;                          // 0: proj, 1: joiner
    const int t    = g & 32767;                        // frag-slot * lane
    const int lane = t & 63;
    const int f    = t >> 6;                           // 0..511 = nt*16+ks
    const int ks   = f & 15;
    const int nt   = f >> 4;
    const int n    = nt * 16 + (lane & 15);
    const int k0   = ks * 32 + (lane >> 4) * 8;
    const float* src = m ? joiner_w : proj_w;
    short*       dst = m ? Wfj : Wfp;
    bf16x8 v;
    if (m && n >= VOCAB) {
        #pragma unroll
        for (int e = 0; e < 8; ++e) v[e] = 0;
    } else {
        #pragma unroll
        for (int e = 0; e < 8; ++e) v[e] = f2bf(src[n * DIM + k0 + e]);
    }
    *(bf16x8*)(void*)(dst + (size_t)t * 8) = v;
}

// ---------------------------------------------------------------------------
// B-frag stream from L2 (fragment-major): no LDS, no barriers.
// Wfw = Wf + w8*8192 + lane*8  (per-wave base); frag(ct,ks) at +ct*8192+ks*512.
// ---------------------------------------------------------------------------
__device__ __forceinline__ void loadB(const short* __restrict__ Wfw, int ks, bf16x8 (&b)[8]) {
    #pragma unroll
    for (int ct = 0; ct < 8; ++ct)
        b[ct] = *(const bf16x8*)(const void*)(Wfw + ct * 8192 + ks * 512);
}

__device__ __forceinline__ void mfma_step(const short* sA, int lm, int lj, int ks,
                                          bf16x8 (&b)[8], f32x4 (&acc)[4][8]) {
    bf16x8 a[4];
    #pragma unroll
    for (int rt = 0; rt < 4; ++rt)
        a[rt] = *(const bf16x8*)(const void*)(&sA[(rt * 16 + lm) * SAS + ks * 32 + 8 * lj]);
    #pragma unroll
    for (int ct = 0; ct < 8; ++ct)
        #pragma unroll
        for (int rt = 0; rt < 4; ++rt)
            acc[rt][ct] = __builtin_amdgcn_mfma_f32_16x16x32_bf16(a[rt], b[ct], acc[rt][ct], 0, 0, 0);
}

// Barrier-free GEMM pass: acc += sA(64x512) @ W^T(cols w*128..+128), reg-dbuf B.
__device__ __forceinline__ void gemm_pass(const short* __restrict__ Wfw, const short* sA,
                                          int lm, int lj, f32x4 (&acc)[4][8]) {
    bf16x8 b0[8], b1[8];
    loadB(Wfw, 0, b0);
    #pragma unroll 1
    for (int ks = 0; ks < 16; ks += 2) {
        loadB(Wfw, ks + 1, b1);
        mfma_step(sA, lm, lj, ks, b0, acc);
        if (ks + 2 < 16) loadB(Wfw, ks + 2, b0);
        mfma_step(sA, lm, lj, ks + 1, b1, acc);
    }
}

// ---------------------------------------------------------------------------
// Fused main: embed+conv+relu -> MFMA GEMM1 -> +b,+enc,tanh -> MFMA GEMM2
// -> +b, log_softmax -> per-block top-4.   LDS ~70KB -> 2 blocks/CU.
// ---------------------------------------------------------------------------
__global__ __launch_bounds__(256, 2) void fused_main(
    const int*   __restrict__ dec_in,
    const float* __restrict__ enc,
    const float* __restrict__ hyp_lp,
    const float* __restrict__ embed,
    const float* __restrict__ conv_w,
    const float* __restrict__ proj_b,
    const float* __restrict__ joiner_b,
    const short* __restrict__ Wfp,
    const short* __restrict__ Wfj,
    float* __restrict__ cand_v,
    int*   __restrict__ cand_i)
{
    __shared__ short sA[RB * SAS];          // 66.5 KB: A (bf16), later tanh acts
    __shared__ float sJb[DIM];
    __shared__ float sHyp[RB];
    __shared__ float sRed[4 * RB];
    __shared__ float s_wv[4]; __shared__ int s_wi[4];
    __shared__ float s_pv[4]; __shared__ int s_pi[4];

    const int tid  = threadIdx.x;
    const int row0 = blockIdx.x * RB;

    for (int j = tid; j < DIM; j += 256) sJb[j] = (j < VOCAB) ? joiner_b[j] : 0.f;
    if (tid < RB) sHyp[tid] = hyp_lp[row0 + tid];

    // ---- Phase 1: embed gather + grouped conv (k=2, in/out groups of 4) + relu
    {
        const int r    = tid >> 2;            // 0..63
        const int c0   = (tid & 3) * 128;     // 128 channels/thread
        const int grow = row0 + r;
        const int tok0 = dec_in[grow * 2 + 0];
        const int tok1 = dec_in[grow * 2 + 1];
        const float z0 = (tok0 >= 0) ? 1.f : 0.f;
        const float z1 = (tok1 >= 0) ? 1.f : 0.f;
        const float4* e0p = (const float4*)(embed + (size_t)(tok0 > 0 ? tok0 : 0) * DIM);
        const float4* e1p = (const float4*)(embed + (size_t)(tok1 > 0 ? tok1 : 0) * DIM);
        #pragma unroll 4
        for (int g = 0; g < 32; ++g) {
            const int c = c0 + g * 4;
            float4 e0 = e0p[c >> 2];
            float4 e1 = e1p[c >> 2];
            e0.x *= z0; e0.y *= z0; e0.z *= z0; e0.w *= z0;
            e1.x *= z1; e1.y *= z1; e1.z *= z1; e1.w *= z1;
            bf16x4 pk;
            #pragma unroll
            for (int j = 0; j < 4; ++j) {
                const int cc = c + j;
                const float4 wa = *(const float4*)(conv_w + cc * 8);
                const float4 wb = *(const float4*)(conv_w + cc * 8 + 4);
                const float v = e0.x*wa.x + e1.x*wa.y + e0.y*wa.z + e1.y*wa.w
                              + e0.z*wb.x + e1.z*wb.y + e0.w*wb.z + e1.w*wb.w;
                pk[j] = f2bf(fmaxf(v, 0.f));
            }
            *(bf16x4*)(void*)(&sA[r * SAS + c]) = pk;
        }
    }
    __syncthreads();

    const int lm   = tid & 15;
    const int lj   = (tid >> 4) & 3;
    const int lane = tid & 63;
    const int w    = tid >> 6;
    const int c0w  = w * 128;

    const short* Wfpw = Wfp + (size_t)w * 8 * 8192 + lane * 8;
    const short* Wfjw = Wfj + (size_t)w * 8 * 8192 + lane * 8;

    f32x4 acc[4][8];
    #pragma unroll
    for (int rt = 0; rt < 4; ++rt)
        #pragma unroll
        for (int ct = 0; ct < 8; ++ct) { acc[rt][ct][0]=0.f; acc[rt][ct][1]=0.f; acc[rt][ct][2]=0.f; acc[rt][ct][3]=0.f; }

    // ================= GEMM1 (barrier-free) =================
    gemm_pass(Wfpw, sA, lm, lj, acc);
    __syncthreads();                          // all waves done reading sA

    // epilogue 1a: raw acc -> sA (bf16, scattered)
    #pragma unroll
    for (int rt = 0; rt < 4; ++rt)
        #pragma unroll
        for (int ct = 0; ct < 8; ++ct)
            #pragma unroll
            for (int rg = 0; rg < 4; ++rg) {
                const int m = rt * 16 + 4 * lj + rg;
                const int n = c0w + ct * 16 + lm;
                sA[m * SAS + n] = f2bf(acc[rt][ct][rg]);
            }
    __syncthreads();

    // epilogue 1b: vectorized act = tanh(C + proj_b + enc), coalesced enc reads
    {
        const int r  = tid >> 2;
        const int cb = (tid & 3) * 128;
        const size_t erow = (size_t)(row0 + r) * DIM;
        #pragma unroll
        for (int ch = 0; ch < 16; ++ch) {
            const int c = cb + ch * 8;
            bf16x8 raw = *(bf16x8*)(void*)(&sA[r * SAS + c]);
            const float4 e0 = *(const float4*)(enc + erow + c);
            const float4 e1 = *(const float4*)(enc + erow + c + 4);
            const float4 b0 = *(const float4*)(proj_b + c);
            const float4 b1 = *(const float4*)(proj_b + c + 4);
            bf16x8 o;
            o[0] = f2bf(tanhf(bf2f(raw[0]) + b0.x + e0.x));
            o[1] = f2bf(tanhf(bf2f(raw[1]) + b0.y + e0.y));
            o[2] = f2bf(tanhf(bf2f(raw[2]) + b0.z + e0.z));
            o[3] = f2bf(tanhf(bf2f(raw[3]) + b0.w + e0.w));
            o[4] = f2bf(tanhf(bf2f(raw[4]) + b1.x + e1.x));
            o[5] = f2bf(tanhf(bf2f(raw[5]) + b1.y + e1.y));
            o[6] = f2bf(tanhf(bf2f(raw[6]) + b1.z + e1.z));
            o[7] = f2bf(tanhf(bf2f(raw[7]) + b1.w + e1.w));
            *(bf16x8*)(void*)(&sA[r * SAS + c]) = o;
        }
    }
    __syncthreads();

    // ================= GEMM2 (barrier-free) =================
    #pragma unroll
    for (int rt = 0; rt < 4; ++rt)
        #pragma unroll
        for (int ct = 0; ct < 8; ++ct) { acc[rt][ct][0]=0.f; acc[rt][ct][1]=0.f; acc[rt][ct][2]=0.f; acc[rt][ct][3]=0.f; }
    gemm_pass(Wfjw, sA, lm, lj, acc);

    // ---- Phase 4: +joiner_b, mask pad cols, row log-softmax, + hyp_lp
    float rmx[4][4];
    #pragma unroll
    for (int rt = 0; rt < 4; ++rt)
        #pragma unroll
        for (int rg = 0; rg < 4; ++rg) rmx[rt][rg] = NEGF;
    #pragma unroll
    for (int ct = 0; ct < 8; ++ct) {
        const int n = c0w + ct * 16 + lm;
        const float jb = sJb[n];
        const bool valid = (n < VOCAB);
        #pragma unroll
        for (int rt = 0; rt < 4; ++rt)
            #pragma unroll
            for (int rg = 0; rg < 4; ++rg) {
                const float v = valid ? (acc[rt][ct][rg] + jb) : NEGF;
                acc[rt][ct][rg] = v;
                rmx[rt][rg] = fmaxf(rmx[rt][rg], v);
            }
    }
    #pragma unroll
    for (int s = 1; s <= 8; s <<= 1)
        #pragma unroll
        for (int rt = 0; rt < 4; ++rt)
            #pragma unroll
            for (int rg = 0; rg < 4; ++rg)
                rmx[rt][rg] = fmaxf(rmx[rt][rg], __shfl_xor(rmx[rt][rg], s, 64));
    if (lm == 0)
        #pragma unroll
        for (int rt = 0; rt < 4; ++rt)
            #pragma unroll
            for (int rg = 0; rg < 4; ++rg)
                sRed[w * RB + rt * 16 + 4 * lj + rg] = rmx[rt][rg];
    __syncthreads();
    float lmx[4][4];
    #pragma unroll
    for (int rt = 0; rt < 4; ++rt)
        #pragma unroll
        for (int rg = 0; rg < 4; ++rg) {
            const int m = rt * 16 + 4 * lj + rg;
            lmx[rt][rg] = fmaxf(fmaxf(sRed[m], sRed[RB + m]), fmaxf(sRed[2*RB + m], sRed[3*RB + m]));
        }
    __syncthreads();
    float rsm[4][4];
    #pragma unroll
    for (int rt = 0; rt < 4; ++rt)
        #pragma unroll
        for (int rg = 0; rg < 4; ++rg) rsm[rt][rg] = 0.f;
    #pragma unroll
    for (int ct = 0; ct < 8; ++ct)
        #pragma unroll
        for (int rt = 0; rt < 4; ++rt)
            #pragma unroll
            for (int rg = 0; rg < 4; ++rg)
                rsm[rt][rg] += __expf(acc[rt][ct][rg] - lmx[rt][rg]);
    #pragma unroll
    for (int s = 1; s <= 8; s <<= 1)
        #pragma unroll
        for (int rt = 0; rt < 4; ++rt)
            #pragma unroll
            for (int rg = 0; rg < 4; ++rg)
                rsm[rt][rg] += __shfl_xor(rsm[rt][rg], s, 64);
    if (lm == 0)
        #pragma unroll
        for (int rt = 0; rt < 4; ++rt)
            #pragma unroll
            for (int rg = 0; rg < 4; ++rg)
                sRed[w * RB + rt * 16 + 4 * lj + rg] = rsm[rt][rg];
    __syncthreads();
    float adj[4][4];
    #pragma unroll
    for (int rt = 0; rt < 4; ++rt)
        #pragma unroll
        for (int rg = 0; rg < 4; ++rg) {
            const int m = rt * 16 + 4 * lj + rg;
            const float den = sRed[m] + sRed[RB + m] + sRed[2*RB + m] + sRed[3*RB + m];
            adj[rt][rg] = sHyp[m] - (lmx[rt][rg] + __logf(den));
        }
    #pragma unroll
    for (int ct = 0; ct < 8; ++ct)
        #pragma unroll
        for (int rt = 0; rt < 4; ++rt)
            #pragma unroll
            for (int rg = 0; rg < 4; ++rg)
                acc[rt][ct][rg] += adj[rt][rg];

    // ---- block top-4 by iterated argmax (tie-break: lower flat index)
    int pick0 = -1, pick1 = -1, pick2 = -1;
    #pragma unroll
    for (int it = 0; it < 4; ++it) {
        float bv = -INFINITY; int bi = 0x7fffffff;
        #pragma unroll
        for (int ct = 0; ct < 8; ++ct) {
            const int n = c0w + ct * 16 + lm;
            if (n < VOCAB) {
                #pragma unroll
                for (int rt = 0; rt < 4; ++rt)
                    #pragma unroll
                    for (int rg = 0; rg < 4; ++rg) {
                        const int m = rt * 16 + 4 * lj + rg;
                        const int idx = (row0 + m) * VOCAB + n;
                        bool excl = false;
                        if (it > 0) excl = excl || (idx == pick0);
                        if (it > 1) excl = excl || (idx == pick1);
                        if (it > 2) excl = excl || (idx == pick2);
                        const float v = acc[rt][ct][rg];
                        if (!excl && (v > bv || (v == bv && idx < bi))) { bv = v; bi = idx; }
                    }
            }
        }
        #pragma unroll
        for (int s = 32; s >= 1; s >>= 1) {
            const float ov = __shfl_xor(bv, s, 64);
            const int   oi = __shfl_xor(bi, s, 64);
            if (ov > bv || (ov == bv && oi < bi)) { bv = ov; bi = oi; }
        }
        if ((tid & 63) == 0) { s_wv[tid >> 6] = bv; s_wi[tid >> 6] = bi; }
        __syncthreads();
        if (tid == 0) {
            float pv = s_wv[0]; int pi = s_wi[0];
            for (int ww = 1; ww < 4; ++ww)
                if (s_wv[ww] > pv || (s_wv[ww] == pv && s_wi[ww] < pi)) { pv = s_wv[ww]; pi = s_wi[ww]; }
            s_pv[it] = pv; s_pi[it] = pi;
        }
        __syncthreads();
        if (it == 0) pick0 = s_pi[0];
        if (it == 1) pick1 = s_pi[1];
        if (it == 2) pick2 = s_pi[2];
    }
    if (tid < 4) {
        cand_v[blockIdx.x * 4 + tid] = s_pv[tid];
        cand_i[blockIdx.x * 4 + tid] = s_pi[tid];
    }
}

// ---------------------------------------------------------------------------
// Final: reduce NBLK*4 = 4096 candidates to global top-4, write 16 outputs.
// ---------------------------------------------------------------------------
__global__ __launch_bounds__(256) void final_topk(
    const float* __restrict__ cand_v,
    const int*   __restrict__ cand_i,
    const float* __restrict__ hyp_lp,
    float* __restrict__ out)
{
    __shared__ float s_wv[4];
    __shared__ int   s_wi[4];
    __shared__ float s_pv[4];
    __shared__ int   s_pi[4];
    const int tid = threadIdx.x;

    float v[16]; int ix[16];
    #pragma unroll
    for (int j = 0; j < 16; ++j) {
        const int e = tid + j * 256;
        v[j]  = cand_v[e];
        ix[j] = cand_i[e];
    }
    int pick0 = -1, pick1 = -1, pick2 = -1;
    #pragma unroll
    for (int it = 0; it < 4; ++it) {
        float bv = -INFINITY; int bi = 0x7fffffff;
        #pragma unroll
        for (int j = 0; j < 16; ++j) {
            bool excl = false;
            if (it > 0) excl = excl || (ix[j] == pick0);
            if (it > 1) excl = excl || (ix[j] == pick1);
            if (it > 2) excl = excl || (ix[j] == pick2);
            if (!excl && (v[j] > bv || (v[j] == bv && ix[j] < bi))) { bv = v[j]; bi = ix[j]; }
        }
        #pragma unroll
        for (int s = 32; s >= 1; s >>= 1) {
            const float ov = __shfl_xor(bv, s, 64);
            const int   oi = __shfl_xor(bi, s, 64);
            if (ov > bv || (ov == bv && oi < bi)) { bv = ov; bi = oi; }
        }
        if ((tid & 63) == 0) { s_wv[tid >> 6] = bv; s_wi[tid >> 6] = bi; }
        __syncthreads();
        if (tid == 0) {
            float pv = s_wv[0]; int pi = s_wi[0];
            for (int ww = 1; ww < 4; ++ww)
                if (s_wv[ww] > pv || (s_wv[ww] == pv && s_wi[ww] < pi)) { pv = s_wv[ww]; pi = s_wi[ww]; }
            s_pv[it] = pv; s_pi[it] = pi;
        }
        __syncthreads();
        if (it == 0) pick0 = s_pi[0];
        if (it == 1) pick1 = s_pi[1];
        if (it == 2) pick2 = s_pi[2];
    }
    if (tid == 0) {
        #pragma unroll
        for (int it = 0; it < 4; ++it) {
            const float val = s_pv[it];
            const int   idx = s_pi[it];
            const int   hyp = idx / VOCAB;
            const int   tok = idx - hyp * VOCAB;
            out[it]      = val;                           // hyps_topk_log_prob
            out[4 + it]  = expf(val - hyp_lp[hyp]);       // tokens_topk_prob
            out[8 + it]  = (float)hyp;                    // topk_hyp_indexes
            out[12 + it] = (float)tok;                    // topk_token_indexes
        }
    }
}

extern "C" void kernel_launch(void* const* d_in, const int* in_sizes, int n_in,
                              void* d_out, int out_size, void* d_ws, size_t ws_size,
                              hipStream_t stream)
{
    const int*   dec_in   = (const int*)d_in[0];
    const float* enc      = (const float*)d_in[1];
    const float* hyp_lp   = (const float*)d_in[2];
    const float* embed    = (const float*)d_in[3];
    const float* conv_w   = (const float*)d_in[4];
    const float* proj_w   = (const float*)d_in[5];
    const float* proj_b   = (const float*)d_in[6];
    const float* joiner_w = (const float*)d_in[7];
    const float* joiner_b = (const float*)d_in[8];

    // workspace: Wfp bf16 frag-major (512KB) | Wfj (512KB) | cand_v (16KB) | cand_i (16KB)
    short* Wfp    = (short*)d_ws;
    short* Wfj    = (short*)((char*)d_ws + 524288);
    float* cand_v = (float*)((char*)d_ws + 1048576);
    int*   cand_i = (int*)  ((char*)d_ws + 1048576 + 16384);
    float* out    = (float*)d_out;

    convert_weights<<<256, 256, 0, stream>>>(proj_w, joiner_w, Wfp, Wfj);
    fused_main<<<NBLK, 256, 0, stream>>>(dec_in, enc, hyp_lp, embed, conv_w,
                                         proj_b, joiner_b, Wfp, Wfj, cand_v, cand_i);
    final_topk<<<1, 256, 0, stream>>>(cand_v, cand_i, hyp_lp, out);
}